// Round 4
// baseline (686.740 us; speedup 1.0000x reference)
//
#include <hip/hip_runtime.h>
#include <hip/hip_bf16.h>

#define NPTS (96 * 96 * 96)   // 884736 points
#define HID 64

__device__ __forceinline__ float bf2f(const __hip_bfloat16 v) {
    return __bfloat162float(v);
}

// tanh(x) = 1 - 2/(1 + 2^{x*2*log2(e)}); exact saturation at +-1.
__device__ __forceinline__ float tanh_fast(float x) {
    float e = __builtin_amdgcn_exp2f(x * 2.88539008177792681472f); // 2/ln(2)
    float r = __builtin_amdgcn_rcpf(e + 1.0f);
    return __builtin_fmaf(-2.0f, r, 1.0f);
}

// ---------------------------------------------------------------------------
// Runtime dtype detection: interpret the first 64 elements of an array as
// bf16; count how many have a "sane" exponent (2^-30 .. 8). True-bf16 data
// (continuous random, nonzero) scores 64/64; fp32 data misread as bf16 scores
// ~36/64 (high halves sane, low halves random). Threshold 52 separates >8σ.
// flags[0]=coords, flags[1]=vol, flags[2]=weights (1 = bf16, 0 = fp32).
// ---------------------------------------------------------------------------
__global__ void detect_kernel(const void* __restrict__ coords,
                              const void* __restrict__ w1,
                              const void* __restrict__ vol,
                              int* __restrict__ flags) {
    int lane = threadIdx.x;  // one wave, 64 lanes
    auto sane = [](const unsigned short* p, int i) -> bool {
        unsigned e = (p[i] >> 7) & 0xFFu;
        return e >= 97u && e <= 129u;
    };
    unsigned long long m;
    m = __ballot(sane((const unsigned short*)w1, lane));
    if (lane == 0) flags[2] = (__popcll(m) >= 52) ? 1 : 0;
    m = __ballot(sane((const unsigned short*)coords, lane));
    if (lane == 0) flags[0] = (__popcll(m) >= 52) ? 1 : 0;
    m = __ballot(sane((const unsigned short*)vol, lane));
    if (lane == 0) flags[1] = (__popcll(m) >= 52) ? 1 : 0;
}

// One MLP eval: out = tanh(y @ W1 + b1) @ W2 + b2
// w layout (fp32, in d_ws): [0,192) W1 row-major 3x64; [192,256) b1;
// [256,448) W2 row-major 64x3; [448,451) b2.
__device__ __forceinline__ void mlp_f(const float* __restrict__ w,
                                      float y0, float y1, float y2,
                                      float& o0, float& o1, float& o2) {
    float a0 = w[448], a1 = w[449], a2 = w[450];
#pragma unroll 16
    for (int j = 0; j < HID; ++j) {
        float pre = __builtin_fmaf(y0, w[j],
                    __builtin_fmaf(y1, w[64 + j],
                    __builtin_fmaf(y2, w[128 + j], w[192 + j])));
        float t = tanh_fast(pre);
        a0 = __builtin_fmaf(t, w[256 + 3 * j + 0], a0);
        a1 = __builtin_fmaf(t, w[256 + 3 * j + 1], a1);
        a2 = __builtin_fmaf(t, w[256 + 3 * j + 2], a2);
    }
    o0 = a0; o1 = a1; o2 = a2;
}

// Convert 2x451 weights (either dtype) to fp32 in ws ([0,512) mlp0, [512,1024) mlp1).
__global__ void conv_weights_kernel(
    const void* __restrict__ W1_0, const void* __restrict__ b1_0,
    const void* __restrict__ W2_0, const void* __restrict__ b2_0,
    const void* __restrict__ W1_1, const void* __restrict__ b1_1,
    const void* __restrict__ W2_1, const void* __restrict__ b2_1,
    float* __restrict__ ws, const int* __restrict__ flags) {
    int t = blockIdx.x * blockDim.x + threadIdx.x;
    if (t >= 1024) return;
    int isbf = flags[2];
    int ode = t >> 9;
    int r = t & 511;
    const void* W1 = ode ? W1_1 : W1_0;
    const void* b1 = ode ? b1_1 : b1_0;
    const void* W2 = ode ? W2_1 : W2_0;
    const void* b2 = ode ? b2_1 : b2_0;
    const void* src = nullptr;
    int idx = 0;
    if (r < 192)       { src = W1; idx = r; }
    else if (r < 256)  { src = b1; idx = r - 192; }
    else if (r < 448)  { src = W2; idx = r - 256; }
    else if (r < 451)  { src = b2; idx = r - 448; }
    float v = 0.0f;
    if (src) {
        if (isbf) v = bf2f(((const __hip_bfloat16*)src)[idx]);
        else      v = ((const float*)src)[idx];
    }
    ws[(ode << 9) + r] = v;
}

__global__ __launch_bounds__(256) void diffeo_kernel(
    const void* __restrict__ coords,
    const float* __restrict__ ws,
    const int* __restrict__ flags,
    const void* __restrict__ vol,
    float* __restrict__ out) {
    int i = blockIdx.x * 256 + threadIdx.x;
    if (i >= NPTS) return;

    int cbf = flags[0];
    int vbf = flags[1];

    float y0, y1, y2;
    if (cbf) {
        const __hip_bfloat16* C = (const __hip_bfloat16*)coords;
        y0 = bf2f(C[3 * i + 0]); y1 = bf2f(C[3 * i + 1]); y2 = bf2f(C[3 * i + 2]);
    } else {
        const float* C = (const float*)coords;
        y0 = C[3 * i + 0]; y1 = C[3 * i + 1]; y2 = C[3 * i + 2];
    }

    const float h = 0.05f;

    // Two sequential neural-ODE warps, RK4, 4 steps each.
#pragma unroll 1
    for (int ode = 0; ode < 2; ++ode) {
        const float* __restrict__ w = ws + (ode << 9);
#pragma unroll 1
        for (int st = 0; st < 4; ++st) {
            float k0 = 0.f, k1 = 0.f, k2 = 0.f;
            float s0 = 0.f, s1 = 0.f, s2 = 0.f;
#pragma unroll 1
            for (int e = 0; e < 4; ++e) {
                float ae = (e == 0) ? 0.0f : ((e == 3) ? h : 0.5f * h);
                float we = (e == 1 || e == 2) ? 2.0f : 1.0f;
                float f0, f1, f2;
                mlp_f(w,
                      __builtin_fmaf(ae, k0, y0),
                      __builtin_fmaf(ae, k1, y1),
                      __builtin_fmaf(ae, k2, y2),
                      f0, f1, f2);
                k0 = f0; k1 = f1; k2 = f2;
                s0 = __builtin_fmaf(we, k0, s0);
                s1 = __builtin_fmaf(we, k1, s1);
                s2 = __builtin_fmaf(we, k2, s2);
            }
            y0 = __builtin_fmaf(h / 6.0f, s0, y0);
            y1 = __builtin_fmaf(h / 6.0f, s1, y1);
            y2 = __builtin_fmaf(h / 6.0f, s2, y2);
        }
    }

    // Output 1: c1, flat [N][3], fp32, starts at element offset NPTS
    out[NPTS + 3 * i + 0] = y0;
    out[NPTS + 3 * i + 1] = y1;
    out[NPTS + 3 * i + 2] = y2;

    // Trilinear grid-sample of vol (128^3), align_corners=False, zeros pad.
    // c[...,2]->x (W), c[...,1]->y (H), c[...,0]->z (D); x = (c+1)*64 - 0.5
    float fx = (y2 + 1.0f) * 64.0f - 0.5f;
    float fy = (y1 + 1.0f) * 64.0f - 0.5f;
    float fz = (y0 + 1.0f) * 64.0f - 0.5f;
    float x0f = floorf(fx), y0f = floorf(fy), z0f = floorf(fz);
    float tx = fx - x0f, ty = fy - y0f, tz = fz - z0f;
    int x0 = (int)x0f, yy0 = (int)y0f, z0 = (int)z0f;
    int x1 = x0 + 1, yy1 = yy0 + 1, z1 = z0 + 1;

    auto clampi = [](int v) { return v < 0 ? 0 : (v > 127 ? 127 : v); };
    auto validf = [](int zi, int yi, int xi) -> bool {
        return ((unsigned)zi < 128u) && ((unsigned)yi < 128u) && ((unsigned)xi < 128u);
    };
    int xc0 = clampi(x0), xc1 = clampi(x1);
    int yc0 = clampi(yy0), yc1 = clampi(yy1);
    int zc0 = clampi(z0), zc1 = clampi(z1);
    int i000 = (zc0 << 14) | (yc0 << 7) | xc0;
    int i001 = (zc0 << 14) | (yc0 << 7) | xc1;
    int i010 = (zc0 << 14) | (yc1 << 7) | xc0;
    int i011 = (zc0 << 14) | (yc1 << 7) | xc1;
    int i100 = (zc1 << 14) | (yc0 << 7) | xc0;
    int i101 = (zc1 << 14) | (yc0 << 7) | xc1;
    int i110 = (zc1 << 14) | (yc1 << 7) | xc0;
    int i111 = (zc1 << 14) | (yc1 << 7) | xc1;

    float v000, v001, v010, v011, v100, v101, v110, v111;
    if (vbf) {
        const __hip_bfloat16* V = (const __hip_bfloat16*)vol;
        v000 = bf2f(V[i000]); v001 = bf2f(V[i001]);
        v010 = bf2f(V[i010]); v011 = bf2f(V[i011]);
        v100 = bf2f(V[i100]); v101 = bf2f(V[i101]);
        v110 = bf2f(V[i110]); v111 = bf2f(V[i111]);
    } else {
        const float* V = (const float*)vol;
        v000 = V[i000]; v001 = V[i001];
        v010 = V[i010]; v011 = V[i011];
        v100 = V[i100]; v101 = V[i101];
        v110 = V[i110]; v111 = V[i111];
    }
    if (!validf(z0, yy0, x0)) v000 = 0.f;
    if (!validf(z0, yy0, x1)) v001 = 0.f;
    if (!validf(z0, yy1, x0)) v010 = 0.f;
    if (!validf(z0, yy1, x1)) v011 = 0.f;
    if (!validf(z1, yy0, x0)) v100 = 0.f;
    if (!validf(z1, yy0, x1)) v101 = 0.f;
    if (!validf(z1, yy1, x0)) v110 = 0.f;
    if (!validf(z1, yy1, x1)) v111 = 0.f;

    float s =
        v000 * (1.f - tz) * (1.f - ty) * (1.f - tx) +
        v001 * (1.f - tz) * (1.f - ty) * tx +
        v010 * (1.f - tz) * ty * (1.f - tx) +
        v011 * (1.f - tz) * ty * tx +
        v100 * tz * (1.f - ty) * (1.f - tx) +
        v101 * tz * (1.f - ty) * tx +
        v110 * tz * ty * (1.f - tx) +
        v111 * tz * ty * tx;

    // Output 0: reg_out = (s - 0.5) * 2, fp32
    out[i] = (s - 0.5f) * 2.0f;
}

extern "C" void kernel_launch(void* const* d_in, const int* in_sizes, int n_in,
                              void* d_out, int out_size, void* d_ws, size_t ws_size,
                              hipStream_t stream) {
    const void* coords = d_in[0];
    const void* W1_0 = d_in[1];
    const void* b1_0 = d_in[2];
    const void* W2_0 = d_in[3];
    const void* b2_0 = d_in[4];
    const void* W1_1 = d_in[5];
    const void* b1_1 = d_in[6];
    const void* W2_1 = d_in[7];
    const void* b2_1 = d_in[8];
    const void* vol  = d_in[9];
    float* out = (float*)d_out;
    float* ws = (float*)d_ws;
    int* flags = ((int*)d_ws) + 1024;   // bytes [4096, 4108)

    detect_kernel<<<1, 64, 0, stream>>>(coords, W1_0, vol, flags);
    conv_weights_kernel<<<2, 512, 0, stream>>>(W1_0, b1_0, W2_0, b2_0,
                                               W1_1, b1_1, W2_1, b2_1, ws, flags);
    diffeo_kernel<<<(NPTS + 255) / 256, 256, 0, stream>>>(coords, ws, flags, vol, out);
}

// Round 5
// 519.796 us; speedup vs baseline: 1.3212x; 1.3212x over previous
//
#include <hip/hip_runtime.h>
#include <hip/hip_bf16.h>

#define NPTS (96 * 96 * 96)   // 884736 points, even
#define HID 64

typedef float v2f __attribute__((ext_vector_type(2)));

__device__ __forceinline__ float bf2f(const __hip_bfloat16 v) {
    return __bfloat162float(v);
}
__device__ __forceinline__ v2f splat(float x) { v2f r; r.x = x; r.y = x; return r; }
__device__ __forceinline__ v2f vfma(v2f a, v2f b, v2f c) {
    return __builtin_elementwise_fma(a, b, c);
}

// ---------------------------------------------------------------------------
// Runtime dtype detection (unchanged from R3 — load-bearing): bf16-interpret
// first 64 elements; sane-exponent count >= 52 -> bf16, else fp32.
// flags[0]=coords, flags[1]=vol, flags[2]=weights.
// ---------------------------------------------------------------------------
__global__ void detect_kernel(const void* __restrict__ coords,
                              const void* __restrict__ w1,
                              const void* __restrict__ vol,
                              int* __restrict__ flags) {
    int lane = threadIdx.x;  // one wave
    auto sane = [](const unsigned short* p, int i) -> bool {
        unsigned e = (p[i] >> 7) & 0xFFu;
        return e >= 97u && e <= 129u;
    };
    unsigned long long m;
    m = __ballot(sane((const unsigned short*)w1, lane));
    if (lane == 0) flags[2] = (__popcll(m) >= 52) ? 1 : 0;
    m = __ballot(sane((const unsigned short*)coords, lane));
    if (lane == 0) flags[0] = (__popcll(m) >= 52) ? 1 : 0;
    m = __ballot(sane((const unsigned short*)vol, lane));
    if (lane == 0) flags[1] = (__popcll(m) >= 52) ? 1 : 0;
}

// ---------------------------------------------------------------------------
// Weight conversion + constant folding into ws (fp32, 1024 floats):
//   [0,192)   W1' = W1 * 2*log2(e)   (row-major 3x64)
//   [192,256) b1' = b1 * 2*log2(e)
//   [256,448) W2' = -2 * W2          (row-major 64x3)
//   [448,451) b2''= b2 + sum_j W2[j][k]
// Then tanh contribution: b2'' + sum_j W2'_jk * rcp(1+exp2(pre'_j))
//   == b2 + sum_j W2_jk * tanh(pre_j).
// ---------------------------------------------------------------------------
__global__ void conv_weights_kernel(
    const void* __restrict__ W1_0, const void* __restrict__ b1_0,
    const void* __restrict__ W2_0, const void* __restrict__ b2_0,
    const void* __restrict__ W1_1, const void* __restrict__ b1_1,
    const void* __restrict__ W2_1, const void* __restrict__ b2_1,
    float* __restrict__ ws, const int* __restrict__ flags) {
    const float K = 2.88539008177792681472f;  // 2/ln(2)
    int t = blockIdx.x * blockDim.x + threadIdx.x;
    if (t >= 1024) return;
    int isbf = flags[2];
    int ode = t >> 9;
    int r = t & 511;
    const void* W1 = ode ? W1_1 : W1_0;
    const void* b1 = ode ? b1_1 : b1_0;
    const void* W2 = ode ? W2_1 : W2_0;
    const void* b2 = ode ? b2_1 : b2_0;
    auto ld = [&](const void* p, int idx) -> float {
        return isbf ? bf2f(((const __hip_bfloat16*)p)[idx]) : ((const float*)p)[idx];
    };
    float v = 0.0f;
    if (r < 192)       v = K * ld(W1, r);
    else if (r < 256)  v = K * ld(b1, r - 192);
    else if (r < 448)  v = -2.0f * ld(W2, r - 256);
    else if (r < 451) {
        int k = r - 448;
        float s = ld(b2, k);
        for (int j = 0; j < HID; ++j) s += ld(W2, 3 * j + k);
        v = s;
    }
    ws[(ode << 9) + r] = v;
}

// One MLP eval for a PAIR of points (v2f lanes .x/.y = point0/point1).
// Uses pre-scaled weights; packed fp32 for all full-rate math.
__device__ __forceinline__ void mlp_f2(const float* __restrict__ w,
                                       v2f y0, v2f y1, v2f y2,
                                       v2f& o0, v2f& o1, v2f& o2) {
    v2f a0 = splat(w[448]), a1 = splat(w[449]), a2 = splat(w[450]);
#pragma unroll 8
    for (int j = 0; j < HID; ++j) {
        v2f pre = vfma(y0, splat(w[j]),
                  vfma(y1, splat(w[64 + j]),
                  vfma(y2, splat(w[128 + j]), splat(w[192 + j]))));
        v2f e;
        e.x = __builtin_amdgcn_exp2f(pre.x);
        e.y = __builtin_amdgcn_exp2f(pre.y);
        v2f d = e + splat(1.0f);
        v2f r;
        r.x = __builtin_amdgcn_rcpf(d.x);
        r.y = __builtin_amdgcn_rcpf(d.y);
        a0 = vfma(r, splat(w[256 + 3 * j + 0]), a0);
        a1 = vfma(r, splat(w[256 + 3 * j + 1]), a1);
        a2 = vfma(r, splat(w[256 + 3 * j + 2]), a2);
    }
    o0 = a0; o1 = a1; o2 = a2;
}

// Trilinear grid-sample of vol (128^3), align_corners=False, zeros padding.
__device__ __forceinline__ float sample3d(const void* __restrict__ vol, int vbf,
                                          float cz, float cy, float cx) {
    float fx = (cx + 1.0f) * 64.0f - 0.5f;
    float fy = (cy + 1.0f) * 64.0f - 0.5f;
    float fz = (cz + 1.0f) * 64.0f - 0.5f;
    float x0f = floorf(fx), y0f = floorf(fy), z0f = floorf(fz);
    float tx = fx - x0f, ty = fy - y0f, tz = fz - z0f;
    int x0 = (int)x0f, y0 = (int)y0f, z0 = (int)z0f;
    int x1 = x0 + 1, y1 = y0 + 1, z1 = z0 + 1;
    auto clampi = [](int v) { return v < 0 ? 0 : (v > 127 ? 127 : v); };
    auto valid = [](int zi, int yi, int xi) -> bool {
        return ((unsigned)zi < 128u) && ((unsigned)yi < 128u) && ((unsigned)xi < 128u);
    };
    int xc0 = clampi(x0), xc1 = clampi(x1);
    int yc0 = clampi(y0), yc1 = clampi(y1);
    int zc0 = clampi(z0), zc1 = clampi(z1);
    int idx[8] = {
        (zc0 << 14) | (yc0 << 7) | xc0, (zc0 << 14) | (yc0 << 7) | xc1,
        (zc0 << 14) | (yc1 << 7) | xc0, (zc0 << 14) | (yc1 << 7) | xc1,
        (zc1 << 14) | (yc0 << 7) | xc0, (zc1 << 14) | (yc0 << 7) | xc1,
        (zc1 << 14) | (yc1 << 7) | xc0, (zc1 << 14) | (yc1 << 7) | xc1 };
    float v[8];
    if (vbf) {
        const __hip_bfloat16* V = (const __hip_bfloat16*)vol;
#pragma unroll
        for (int q = 0; q < 8; ++q) v[q] = bf2f(V[idx[q]]);
    } else {
        const float* V = (const float*)vol;
#pragma unroll
        for (int q = 0; q < 8; ++q) v[q] = V[idx[q]];
    }
    if (!valid(z0, y0, x0)) v[0] = 0.f;
    if (!valid(z0, y0, x1)) v[1] = 0.f;
    if (!valid(z0, y1, x0)) v[2] = 0.f;
    if (!valid(z0, y1, x1)) v[3] = 0.f;
    if (!valid(z1, y0, x0)) v[4] = 0.f;
    if (!valid(z1, y0, x1)) v[5] = 0.f;
    if (!valid(z1, y1, x0)) v[6] = 0.f;
    if (!valid(z1, y1, x1)) v[7] = 0.f;
    return v[0] * (1.f - tz) * (1.f - ty) * (1.f - tx) +
           v[1] * (1.f - tz) * (1.f - ty) * tx +
           v[2] * (1.f - tz) * ty * (1.f - tx) +
           v[3] * (1.f - tz) * ty * tx +
           v[4] * tz * (1.f - ty) * (1.f - tx) +
           v[5] * tz * (1.f - ty) * tx +
           v[6] * tz * ty * (1.f - tx) +
           v[7] * tz * ty * tx;
}

__global__ __launch_bounds__(256) void diffeo_kernel(
    const void* __restrict__ coords,
    const float* __restrict__ ws,
    const int* __restrict__ flags,
    const void* __restrict__ vol,
    float* __restrict__ out) {
    int t = blockIdx.x * 256 + threadIdx.x;   // pair index
    if (t >= NPTS / 2) return;

    int cbf = flags[0];
    int vbf = flags[1];

    // Two consecutive points: elements [6t, 6t+6) of coords.
    v2f y0, y1, y2;
    if (cbf) {
        const __hip_bfloat16* C = (const __hip_bfloat16*)coords;
        int b = 6 * t;
        y0.x = bf2f(C[b + 0]); y1.x = bf2f(C[b + 1]); y2.x = bf2f(C[b + 2]);
        y0.y = bf2f(C[b + 3]); y1.y = bf2f(C[b + 4]); y2.y = bf2f(C[b + 5]);
    } else {
        const float* C = (const float*)coords;
        int b = 6 * t;
        y0.x = C[b + 0]; y1.x = C[b + 1]; y2.x = C[b + 2];
        y0.y = C[b + 3]; y1.y = C[b + 4]; y2.y = C[b + 5];
    }

    const float h = 0.05f;

#pragma unroll 1
    for (int ode = 0; ode < 2; ++ode) {
        const float* __restrict__ w = ws + (ode << 9);
#pragma unroll 1
        for (int st = 0; st < 4; ++st) {
            v2f k0 = splat(0.f), k1 = splat(0.f), k2 = splat(0.f);
            v2f s0 = splat(0.f), s1 = splat(0.f), s2 = splat(0.f);
#pragma unroll 1
            for (int e = 0; e < 4; ++e) {
                float ae = (e == 0) ? 0.0f : ((e == 3) ? h : 0.5f * h);
                float we = (e == 1 || e == 2) ? 2.0f : 1.0f;
                v2f aev = splat(ae), wev = splat(we);
                v2f f0, f1, f2;
                mlp_f2(w,
                       vfma(aev, k0, y0),
                       vfma(aev, k1, y1),
                       vfma(aev, k2, y2),
                       f0, f1, f2);
                k0 = f0; k1 = f1; k2 = f2;
                s0 = vfma(wev, k0, s0);
                s1 = vfma(wev, k1, s1);
                s2 = vfma(wev, k2, s2);
            }
            v2f h6 = splat(h / 6.0f);
            y0 = vfma(h6, s0, y0);
            y1 = vfma(h6, s1, y1);
            y2 = vfma(h6, s2, y2);
        }
    }

    // Output 1: c1, fp32, [N][3] at element offset NPTS.
    int b = 6 * t;
    out[NPTS + b + 0] = y0.x; out[NPTS + b + 1] = y1.x; out[NPTS + b + 2] = y2.x;
    out[NPTS + b + 3] = y0.y; out[NPTS + b + 4] = y1.y; out[NPTS + b + 5] = y2.y;

    // Output 0: reg_out = (s - 0.5) * 2, fp32.
    float sA = sample3d(vol, vbf, y0.x, y1.x, y2.x);
    float sB = sample3d(vol, vbf, y0.y, y1.y, y2.y);
    out[2 * t + 0] = (sA - 0.5f) * 2.0f;
    out[2 * t + 1] = (sB - 0.5f) * 2.0f;
}

extern "C" void kernel_launch(void* const* d_in, const int* in_sizes, int n_in,
                              void* d_out, int out_size, void* d_ws, size_t ws_size,
                              hipStream_t stream) {
    const void* coords = d_in[0];
    const void* W1_0 = d_in[1];
    const void* b1_0 = d_in[2];
    const void* W2_0 = d_in[3];
    const void* b2_0 = d_in[4];
    const void* W1_1 = d_in[5];
    const void* b1_1 = d_in[6];
    const void* W2_1 = d_in[7];
    const void* b2_1 = d_in[8];
    const void* vol  = d_in[9];
    float* out = (float*)d_out;
    float* ws = (float*)d_ws;
    int* flags = ((int*)d_ws) + 1024;   // bytes [4096, 4108)

    detect_kernel<<<1, 64, 0, stream>>>(coords, W1_0, vol, flags);
    conv_weights_kernel<<<2, 512, 0, stream>>>(W1_0, b1_0, W2_0, b2_0,
                                               W1_1, b1_1, W2_1, b2_1, ws, flags);
    int pairs = NPTS / 2;
    diffeo_kernel<<<(pairs + 255) / 256, 256, 0, stream>>>(coords, ws, flags, vol, out);
}